// Round 12
// baseline (3901.568 us; speedup 1.0000x reference)
//
#include <hip/hip_runtime.h>
#include <stdint.h>

#define BB 4
#define NN 8192
#define SS 2048
#define KK 16
#define IND 64
#define CIN 67
#define OD 128

typedef unsigned int   u32;
typedef unsigned long long u64;
typedef float f2 __attribute__((ext_vector_type(2)));

// ---------------- prep: pack xyz into float4(x,y,z,|p|^2) (rn ops, matches np sum order) -
__global__ __launch_bounds__(256) void k_prep(const float* __restrict__ xyz,
                                              float4* __restrict__ pts){
  int i = blockIdx.x * 256 + threadIdx.x;
  if (i >= BB*NN) return;
  float x = xyz[3*i+0];
  float y = xyz[3*i+1];
  float z = xyz[3*i+2];
  float x2 = __fadd_rn(__fadd_rn(__fmul_rn(x,x), __fmul_rn(y,y)), __fmul_rn(z,z));
  pts[i] = make_float4(x,y,z,x2);
}

// DPP helper: move x by DPP control, invalid lanes keep x (bound_ctrl=false -> old value)
template<int CTRL>
__device__ __forceinline__ float dpp_mv(float x){
  int xi = __builtin_bit_cast(int, x);
  int r  = __builtin_amdgcn_update_dpp(xi, xi, CTRL, 0xf, 0xf, false);
  return __builtin_bit_cast(float, r);
}

// ---------------- FPS v10: R7 config (FPT=512/PPT=16, best measured) + winner-lane
//                  direct publish + 2-accum compute. Zero VMEM in the loop. -------------
#define FPT 512
#define PPT (NN/FPT)   // 16 points per thread
#define NW  (FPT/64)   // 8 waves
#define FPS_LDS ((3*NN + 3*SS)*4)   // 96 KB coords + 24 KB results = 120 KB
__global__ __launch_bounds__(FPT) void k_fps(const float4* __restrict__ pts,
                                             float* __restrict__ out_xyz){
  #pragma clang fp contract(off)
  extern __shared__ float smem[];
  float* sx = smem;                 // [NN]
  float* sy = smem +   NN;          // [NN]
  float* sz = smem + 2*NN;          // [NN]
  float* rx = smem + 3*NN;          // [SS]
  float* ry = smem + 3*NN +   SS;   // [SS]
  float* rz = smem + 3*NN + 2*SS;   // [SS]
  __shared__ u64 pkey[2][NW];       // double-buffered wave partial keys
  int b = blockIdx.x;
  int tid = threadIdx.x;
  int wid = tid >> 6, lane = tid & 63;
  const float4* P = pts + (size_t)b*NN;
  f2 X[PPT/2], Y[PPT/2], Z[PPT/2], D[PPT/2];
  #pragma unroll
  for (int jp=0;jp<PPT/2;jp++){
    int n0 = tid*PPT + 2*jp;
    float4 p0 = P[n0];
    float4 p1 = P[n0+1];
    X[jp] = (f2){p0.x, p1.x};
    Y[jp] = (f2){p0.y, p1.y};
    Z[jp] = (f2){p0.z, p1.z};
    D[jp] = (f2){1e10f, 1e10f};
    sx[n0]=p0.x; sx[n0+1]=p1.x;
    sy[n0]=p0.y; sy[n0+1]=p1.y;
    sz[n0]=p0.z; sz[n0+1]=p1.z;
  }
  float4 p0v = P[0];                // broadcast load
  float cx=p0v.x, cy=p0v.y, cz=p0v.z;
  if (tid==0){ rx[0]=cx; ry[0]=cy; rz[0]=cz; }
  __syncthreads();                  // LDS coords ready

  for (int it=1; it<SS; ++it){
    // ---- compute: plain packed fp32 under contract(off) == numpy rn; 2 accums -------
    f2 mm0 = (f2){-1.0f, -1.0f}, mm1 = (f2){-1.0f, -1.0f};
    #pragma unroll
    for (int jp=0;jp<PPT/2;jp+=2){
      f2 dx0 = X[jp] - cx,   dy0 = Y[jp] - cy,   dz0 = Z[jp] - cz;
      f2 dx1 = X[jp+1] - cx, dy1 = Y[jp+1] - cy, dz1 = Z[jp+1] - cz;
      f2 d0  = ((dx0*dx0) + (dy0*dy0)) + (dz0*dz0);   // ((dx2+dy2)+dz2), no contraction
      f2 d1  = ((dx1*dx1) + (dy1*dy1)) + (dz1*dz1);
      f2 nd0 = __builtin_elementwise_min(D[jp],   d0);
      f2 nd1 = __builtin_elementwise_min(D[jp+1], d1);
      D[jp]   = nd0;
      D[jp+1] = nd1;
      mm0 = __builtin_elementwise_max(mm0, nd0);
      mm1 = __builtin_elementwise_max(mm1, nd1);
    }
    f2 mm = __builtin_elementwise_max(mm0, mm1);
    float md = fmaxf(mm.x, mm.y);   // thread max (no index tracked)
    // ---- wave max via DPP (6 ops) ---------------------------------------------------
    float m = md;
    m = fmaxf(m, dpp_mv<0x111>(m));   // row_shr:1
    m = fmaxf(m, dpp_mv<0x112>(m));   // row_shr:2
    m = fmaxf(m, dpp_mv<0x114>(m));   // row_shr:4
    m = fmaxf(m, dpp_mv<0x118>(m));   // row_shr:8
    m = fmaxf(m, dpp_mv<0x142>(m));   // row_bcast:15
    m = fmaxf(m, dpp_mv<0x143>(m));   // row_bcast:31  -> lane 63 = wave max
    float wmax = __builtin_bit_cast(float,
        __builtin_amdgcn_readlane(__builtin_bit_cast(int, m), 63));
    // ---- winner lane (lowest lane == lowest point range) resolves and publishes -----
    u64 ball = __ballot(md == wmax);
    int wl = __ffsll((unsigned long long)ball) - 1;
    if (lane == wl){                // exactly one lane per wave
      int bj = 0;
      #pragma unroll
      for (int t=PPT-1;t>=0;--t){   // descending overwrite -> lowest t wins
        float v = (t&1)? D[t>>1].y : D[t>>1].x;
        if (v == wmax) bj = t;
      }
      int widx = tid*PPT + bj;      // wave winner point index
      // key packs (dist, ~idx): u64 max == argmax with lowest-index tie-break
      pkey[it&1][wid] = ((u64)__float_as_uint(wmax) << 32) | (u32)~(u32)widx;
    }
    __syncthreads();                // only LDS outstanding -> cheap drain
    // ---- combine 8 u64 partials (contiguous 64B) ------------------------------------
    u64 bk = pkey[it&1][0];
    #pragma unroll
    for (int w=1;w<NW;w++){
      u64 k2 = pkey[it&1][w];
      if (k2 > bk) bk = k2;
    }
    int gw = (int)~(u32)bk;         // global winner index (block-uniform)
    // ---- winner coords from LDS (broadcast ds_read); result write is LDS too --------
    cx = sx[gw]; cy = sy[gw]; cz = sz[gw];
    if (tid==0){ rx[it]=cx; ry[it]=cy; rz[it]=cz; }
  }
  __syncthreads();
  // ---- bulk store of all selected coords (single VMEM phase at the very end) -------
  for (int i=tid; i<SS; i+=FPT){
    size_t o = (size_t)b*SS*3 + (size_t)i*3;
    out_xyz[o]=rx[i]; out_xyz[o+1]=ry[i]; out_xyz[o+2]=rz[i];
  }
}

// ---------------- clock probe: fixed 524288-long dependent FMA chain (~2.10 Mcyc).
// Duration in wall time reveals effective SCLK: dur ≈ 2.10e6 / f.
// ~870 us @2.4GHz, ~1900 us @1.1GHz (read via Δtotal vs the 2440us baseline). ----------
__global__ __launch_bounds__(64) void k_probe(float* __restrict__ ws){
  float a = ws[0];                  // runtime-unknown (poisoned) -> chain not foldable
  const float c1 = 1.0000001f, c2 = 1.0e-7f;
  #pragma unroll 1
  for (int i=0;i<32768;i++){
    #pragma unroll
    for (int j=0;j<16;j++) a = fmaf(a, c1, c2);
  }
  if (threadIdx.x==63) ws[1] = a;   // keep the chain alive
}

// ---------------- KNN (standalone, LDS-free, high occupancy): top-16 by (dist,idx) -----
__global__ __launch_bounds__(256) void k_knn(const float4* __restrict__ pts,
                                             const float* __restrict__ ctr,   // = out_xyz
                                             int* __restrict__ knn_idx){
  int q = blockIdx.x*4 + (threadIdx.x>>6);
  int lane = threadIdx.x & 63;
  int b = q / SS;
  const float4* P = pts + (size_t)b*NN;
  float qx=ctr[3*q], qy=ctr[3*q+1], qz=ctr[3*q+2];
  float q2 = __fadd_rn(__fadd_rn(__fmul_rn(qx,qx),__fmul_rn(qy,qy)),__fmul_rn(qz,qz));
  u64 key[KK];
  #pragma unroll
  for (int t=0;t<KK;t++) key[t] = ~0ull;
  for (int i=0;i<NN/64;i++){
    int n = i*64 + lane;             // coalesced float4 loads
    float4 p = P[n];
    float dot = __fadd_rn(__fadd_rn(__fmul_rn(qx,p.x),__fmul_rn(qy,p.y)),__fmul_rn(qz,p.z));
    float sd  = __fsub_rn(__fadd_rn(q2,p.w), __fmul_rn(2.0f,dot));
    u32 bu = __float_as_uint(sd);
    bu ^= (u32)((int)bu >> 31) | 0x80000000u;   // monotone float->uint
    u64 kk = ((u64)bu<<32) | (u32)n;
    if (kk < key[KK-1]){
      key[KK-1] = kk;
      #pragma unroll
      for (int t=KK-1;t>0;--t){      // one reverse bubble pass restores sortedness
        u64 a=key[t-1], c=key[t];
        bool sw = c < a;
        key[t-1] = sw? c : a;
        key[t]   = sw? a : c;
      }
    }
  }
  #pragma unroll 1
  for (int r=0;r<KK;r++){
    u64 m = key[0];
    #pragma unroll
    for (int mm=1;mm<64;mm<<=1){
      u64 om = __shfl_xor((unsigned long long)m, mm, 64);
      if (om < m) m = om;
    }
    if (lane==0) knn_idx[q*KK + r] = (int)(u32)m;
    if (key[0]==m){                  // unique keys -> exactly one lane pops
      #pragma unroll
      for (int t=0;t<KK-1;t++) key[t]=key[t+1];
      key[KK-1]=~0ull;
    }
  }
}

// ---------------- gather + MLP(67->128 relu ->128) + maxpool + LN, one wave/query ------
__global__ __launch_bounds__(256) void k_mlp(const float* __restrict__ feat,
                                             const float4* __restrict__ pts,
                                             const float* __restrict__ ctr,   // = out_xyz
                                             const int* __restrict__ knn_idx,
                                             const float* __restrict__ W1, const float* __restrict__ b1,
                                             const float* __restrict__ W2, const float* __restrict__ b2,
                                             const float* __restrict__ g_ln, const float* __restrict__ b_ln,
                                             float* __restrict__ out_feat){
  __shared__ float gbuf[4][CIN][16];     // grouped: [j][k], wave-private slices
  __shared__ float hbuf[4][OD][20];      // h1: [channel][k], stride 20
  int wid = threadIdx.x>>6, lane = threadIdx.x&63;
  int q = blockIdx.x*4 + wid;
  int b = q / SS;
  float* gw = &gbuf[wid][0][0];
  float* hw = &hbuf[wid][0][0];
  int k = lane & 15, part = lane >> 4;   // part in [0,4): 16 channels each
  int n = knn_idx[q*KK + k];
  {
    const float* fp = feat + ((size_t)b*NN + (size_t)n)*IND + part*16;
    float4 f0 = *(const float4*)(fp+0);
    float4 f1 = *(const float4*)(fp+4);
    float4 f2v = *(const float4*)(fp+8);
    float4 f3 = *(const float4*)(fp+12);
    float v[16] = {f0.x,f0.y,f0.z,f0.w, f1.x,f1.y,f1.z,f1.w,
                   f2v.x,f2v.y,f2v.z,f2v.w, f3.x,f3.y,f3.z,f3.w};
    #pragma unroll
    for (int c=0;c<16;c++) gw[(3+part*16+c)*16 + k] = v[c];
    if (part==0){
      float4 p = pts[(size_t)b*NN + n];
      gw[0*16+k] = __fsub_rn(p.x, ctr[3*q+0]);  // exact rel coords (matches np fp32)
      gw[1*16+k] = __fsub_rn(p.y, ctr[3*q+1]);
      gw[2*16+k] = __fsub_rn(p.z, ctr[3*q+2]);
    }
  }
  __syncthreads();
  int o = lane;                          // this thread owns channels o and o+64
  float a0[16], a1[16];
  #pragma unroll
  for (int t=0;t<16;t++){ a0[t]=0.0f; a1[t]=0.0f; }
  #pragma unroll 4
  for (int j=0;j<CIN;j++){
    float w0 = W1[j*OD + o];
    float w1 = W1[j*OD + o + 64];
    #pragma unroll
    for (int t=0;t<16;t++){
      float gv = gw[j*16+t];             // LDS broadcast
      a0[t]=fmaf(gv,w0,a0[t]); a1[t]=fmaf(gv,w1,a1[t]);
    }
  }
  float bb0 = b1[o], bb1 = b1[o+64];
  #pragma unroll
  for (int t=0;t<16;t++){
    hw[o*20+t]      = fmaxf(a0[t]+bb0, 0.0f);
    hw[(o+64)*20+t] = fmaxf(a1[t]+bb1, 0.0f);
  }
  __syncthreads();
  float c0[16], c1[16];
  #pragma unroll
  for (int t=0;t<16;t++){ c0[t]=0.0f; c1[t]=0.0f; }
  #pragma unroll 4
  for (int j=0;j<OD;j++){
    float w0 = W2[j*OD + o];
    float w1 = W2[j*OD + o + 64];
    #pragma unroll
    for (int t=0;t<16;t++){
      float hv = hw[j*20+t];
      c0[t]=fmaf(hv,w0,c0[t]); c1[t]=fmaf(hv,w1,c1[t]);
    }
  }
  float m0=c0[0], m1=c1[0];
  #pragma unroll
  for (int t=1;t<16;t++){ m0=fmaxf(m0,c0[t]); m1=fmaxf(m1,c1[t]); }
  m0 += b2[o]; m1 += b2[o+64];           // fold bias after max (commutes with max)
  // LayerNorm over 128 channels (wave reduce)
  float ssum = m0+m1;
  #pragma unroll
  for (int mm=1;mm<64;mm<<=1) ssum += __shfl_xor(ssum,mm,64);
  float mean = ssum * (1.0f/128.0f);
  float d0=m0-mean, d1=m1-mean;
  float sq = d0*d0 + d1*d1;
  #pragma unroll
  for (int mm=1;mm<64;mm<<=1) sq += __shfl_xor(sq,mm,64);
  float var = sq * (1.0f/128.0f);
  float x = var + 1e-5f;
  float r = rsqrtf(x);
  r = r * (1.5f - 0.5f*x*r*r);           // one NR step -> ~1 ulp of 1/sqrt
  size_t obf = (size_t)q*OD;
  out_feat[obf+o]    = fmaf(d0*r, g_ln[o],    b_ln[o]);
  out_feat[obf+o+64] = fmaf(d1*r, g_ln[o+64], b_ln[o+64]);
}

extern "C" void kernel_launch(void* const* d_in, const int* in_sizes, int n_in,
                              void* d_out, int out_size, void* d_ws, size_t ws_size,
                              hipStream_t stream){
  const float* xyz  = (const float*)d_in[0];
  const float* feat = (const float*)d_in[1];
  const float* W1   = (const float*)d_in[2];
  const float* b1   = (const float*)d_in[3];
  const float* W2   = (const float*)d_in[4];
  const float* b2   = (const float*)d_in[5];
  const float* lg   = (const float*)d_in[6];
  const float* lb   = (const float*)d_in[7];
  float* out = (float*)d_out;
  char* ws = (char*)d_ws;
  float4* pts = (float4*)ws;                          // 512 KB
  int*    kidx = (int*)(ws + 524288);                 // 512 KB
  float*  pws  = (float*)(ws + 1048576);              // probe scratch
  float* out_xyz  = out;
  float* out_feat = out + (size_t)BB*SS*3;

  // allow 120 KB dynamic LDS for k_fps (gfx950: 160 KB/CU). Idempotent, capture-safe.
  hipFuncSetAttribute((const void*)k_fps,
                      hipFuncAttributeMaxDynamicSharedMemorySize, FPS_LDS);

  hipLaunchKernelGGL(k_prep, dim3((BB*NN+255)/256), dim3(256), 0,       stream, xyz, pts);
  hipLaunchKernelGGL(k_fps,  dim3(BB),              dim3(FPT), FPS_LDS, stream, pts, out_xyz);
  hipLaunchKernelGGL(k_knn,  dim3(BB*SS/4),         dim3(256), 0,       stream, pts, out_xyz, kidx);
  hipLaunchKernelGGL(k_mlp,  dim3(BB*SS/4),         dim3(256), 0,       stream,
                     feat, pts, out_xyz, kidx, W1, b1, W2, b2, lg, lb, out_feat);
  hipLaunchKernelGGL(k_probe, dim3(1),              dim3(64),  0,       stream, pws);
}

// Round 13
// 2149.292 us; speedup vs baseline: 1.8153x; 1.8153x over previous
//
#include <hip/hip_runtime.h>
#include <stdint.h>

#define BB 4
#define NN 8192
#define SS 2048
#define KK 16
#define IND 64
#define CIN 67
#define OD 128

typedef unsigned int   u32;
typedef unsigned long long u64;
typedef float f2 __attribute__((ext_vector_type(2)));

#define TAG 0x5EED0000u
#define CW  252                      // consumer blocks
#define GRID (BB + CW)               // 256 blocks, 1/CU -> all co-resident
#define NWAVES (CW*8)                // 2016 consumer waves
#define SLICE 3632                   // floats per consumer wave slice (gbuf 1072 + hbuf 2560)
#define DYN_LDS (8*SLICE*4)          // 116224 B >= FPS's 98304 B coord need

// ---------------- prep: pack xyz into float4(x,y,z,|p|^2) + zero progress flags --------
__global__ __launch_bounds__(256) void k_prep(const float* __restrict__ xyz,
                                              float4* __restrict__ pts,
                                              u32* __restrict__ progress){
  if (blockIdx.x==0 && threadIdx.x<BB) progress[threadIdx.x] = 0u;  // tag!=0x5EED -> not ready
  int i = blockIdx.x * 256 + threadIdx.x;
  if (i >= BB*NN) return;
  float x = xyz[3*i+0];
  float y = xyz[3*i+1];
  float z = xyz[3*i+2];
  float x2 = __fadd_rn(__fadd_rn(__fmul_rn(x,x), __fmul_rn(y,y)), __fmul_rn(z,z));
  pts[i] = make_float4(x,y,z,x2);
}

template<int CTRL>
__device__ __forceinline__ float dpp_mv(float x){
  int xi = __builtin_bit_cast(int, x);
  int r  = __builtin_amdgcn_update_dpp(xi, xi, CTRL, 0xf, 0xf, false);
  return __builtin_bit_cast(float, r);
}

// ---------------- fused: blocks 0..3 = FPS producer; blocks 4..255 = knn+mlp consumers --
#define FPT 512
#define PPT (NN/FPT)   // 16
#define NW  (FPT/64)   // 8
__global__ __launch_bounds__(512) void k_fused(const float4* __restrict__ pts,
                                               float* __restrict__ out_xyz,
                                               const float* __restrict__ feat,
                                               const float* __restrict__ W1, const float* __restrict__ b1,
                                               const float* __restrict__ W2, const float* __restrict__ b2,
                                               const float* __restrict__ g_ln, const float* __restrict__ b_ln,
                                               float* __restrict__ out_feat,
                                               u32* __restrict__ progress){
  extern __shared__ float smem[];
  __shared__ u64 pkey[2][NW];
  int tid = threadIdx.x;
  int wid = tid >> 6, lane = tid & 63;

  if (blockIdx.x < BB){
    // =========================== FPS producer (R12 structure) =========================
    #pragma clang fp contract(off)
    float* sx = smem;                 // [NN]
    float* sy = smem +   NN;          // [NN]
    float* sz = smem + 2*NN;          // [NN]
    int b = blockIdx.x;
    const float4* P = pts + (size_t)b*NN;
    f2 X[PPT/2], Y[PPT/2], Z[PPT/2], D[PPT/2];
    #pragma unroll
    for (int jp=0;jp<PPT/2;jp++){
      int n0 = tid*PPT + 2*jp;
      float4 p0 = P[n0];
      float4 p1 = P[n0+1];
      X[jp] = (f2){p0.x, p1.x};
      Y[jp] = (f2){p0.y, p1.y};
      Z[jp] = (f2){p0.z, p1.z};
      D[jp] = (f2){1e10f, 1e10f};
      sx[n0]=p0.x; sx[n0+1]=p1.x;
      sy[n0]=p0.y; sy[n0+1]=p1.y;
      sz[n0]=p0.z; sz[n0+1]=p1.z;
    }
    float4 p0v = P[0];
    float cx=p0v.x, cy=p0v.y, cz=p0v.z;
    size_t ob = (size_t)b*SS*3;
    if (tid==1){
      out_xyz[ob+0]=cx; out_xyz[ob+1]=cy; out_xyz[ob+2]=cz;
      __hip_atomic_store(&progress[b], TAG|0u, __ATOMIC_RELEASE, __HIP_MEMORY_SCOPE_AGENT);
    }
    __syncthreads();

    for (int it=1; it<SS; ++it){
      f2 mm0 = (f2){-1.0f, -1.0f}, mm1 = (f2){-1.0f, -1.0f};
      #pragma unroll
      for (int jp=0;jp<PPT/2;jp+=2){
        f2 dx0 = X[jp] - cx,   dy0 = Y[jp] - cy,   dz0 = Z[jp] - cz;
        f2 dx1 = X[jp+1] - cx, dy1 = Y[jp+1] - cy, dz1 = Z[jp+1] - cz;
        f2 d0  = ((dx0*dx0) + (dy0*dy0)) + (dz0*dz0);   // ((dx2+dy2)+dz2), numpy rn order
        f2 d1  = ((dx1*dx1) + (dy1*dy1)) + (dz1*dz1);
        f2 nd0 = __builtin_elementwise_min(D[jp],   d0);
        f2 nd1 = __builtin_elementwise_min(D[jp+1], d1);
        D[jp]   = nd0;
        D[jp+1] = nd1;
        mm0 = __builtin_elementwise_max(mm0, nd0);
        mm1 = __builtin_elementwise_max(mm1, nd1);
      }
      f2 mm = __builtin_elementwise_max(mm0, mm1);
      float md = fmaxf(mm.x, mm.y);
      float m = md;
      m = fmaxf(m, dpp_mv<0x111>(m));
      m = fmaxf(m, dpp_mv<0x112>(m));
      m = fmaxf(m, dpp_mv<0x114>(m));
      m = fmaxf(m, dpp_mv<0x118>(m));
      m = fmaxf(m, dpp_mv<0x142>(m));
      m = fmaxf(m, dpp_mv<0x143>(m));
      float wmax = __builtin_bit_cast(float,
          __builtin_amdgcn_readlane(__builtin_bit_cast(int, m), 63));
      u64 ball = __ballot(md == wmax);
      int wl = __ffsll((unsigned long long)ball) - 1;
      if (lane == wl){
        int bj = 0;
        #pragma unroll
        for (int t=PPT-1;t>=0;--t){
          float v = (t&1)? D[t>>1].y : D[t>>1].x;
          if (v == wmax) bj = t;
        }
        int widx = tid*PPT + bj;
        pkey[it&1][wid] = ((u64)__float_as_uint(wmax) << 32) | (u32)~(u32)widx;
      }
      __syncthreads();
      u64 bk = pkey[it&1][0];
      #pragma unroll
      for (int w=1;w<NW;w++){
        u64 k2 = pkey[it&1][w];
        if (k2 > bk) bk = k2;
      }
      int gw = (int)~(u32)bk;
      cx = sx[gw]; cy = sy[gw]; cz = sz[gw];
      if (tid==1){
        size_t o = ob + (size_t)it*3;
        out_xyz[o]=cx; out_xyz[o+1]=cy; out_xyz[o+2]=cz;     // fire-and-forget
        if ((it & 15) == 15 || it == SS-1)                   // ~128 publishes; release
          __hip_atomic_store(&progress[b], TAG|(u32)it,
                             __ATOMIC_RELEASE, __HIP_MEMORY_SCOPE_AGENT);
      }
    }
    return;
  }

  // ============================ consumer: knn + mlp per wave ==========================
  int gid = (blockIdx.x - BB)*8 + wid;       // 0..2015
  float* gw = smem + wid*SLICE;              // wave-private gbuf [CIN][16]
  float* hw = gw + CIN*16 + 0;  hw = gw + 1072;  // wave-private hbuf [OD][20]
  int k = lane & 15, part = lane >> 4;
  const u32* ctru = (const u32*)out_xyz;

  for (int p = gid; p < BB*SS; p += NWAVES){
    int s = p >> 2, b = p & 3;
    int q = b*SS + s;
    // ---- wait until center s of batch b is published (tag defeats 0xAA poison) ------
    for(;;){
      u32 v = __hip_atomic_load(&progress[b], __ATOMIC_RELAXED, __HIP_MEMORY_SCOPE_AGENT);
      if ((v & 0xFFFF0000u) == TAG && (v & 0xFFFFu) >= (u32)s) break;
      __builtin_amdgcn_s_sleep(64);
    }
    // ---- center via agent-scope loads (bypass stale local L2) ------------------------
    float qx = __builtin_bit_cast(float, __hip_atomic_load(&ctru[3*q+0], __ATOMIC_RELAXED, __HIP_MEMORY_SCOPE_AGENT));
    float qy = __builtin_bit_cast(float, __hip_atomic_load(&ctru[3*q+1], __ATOMIC_RELAXED, __HIP_MEMORY_SCOPE_AGENT));
    float qz = __builtin_bit_cast(float, __hip_atomic_load(&ctru[3*q+2], __ATOMIC_RELAXED, __HIP_MEMORY_SCOPE_AGENT));
    const float4* P = pts + (size_t)b*NN;
    float q2 = __fadd_rn(__fadd_rn(__fmul_rn(qx,qx),__fmul_rn(qy,qy)),__fmul_rn(qz,qz));
    // ---- KNN: exact (q2+x2)-2dot, per-lane sorted top-16 of (dist_bits, idx) --------
    u64 key[KK];
    #pragma unroll
    for (int t=0;t<KK;t++) key[t] = ~0ull;
    for (int i=0;i<NN/64;i++){
      int n = i*64 + lane;
      float4 pp = P[n];
      float dot = __fadd_rn(__fadd_rn(__fmul_rn(qx,pp.x),__fmul_rn(qy,pp.y)),__fmul_rn(qz,pp.z));
      float sd  = __fsub_rn(__fadd_rn(q2,pp.w), __fmul_rn(2.0f,dot));
      u32 bu = __float_as_uint(sd);
      bu ^= (u32)((int)bu >> 31) | 0x80000000u;
      u64 kk = ((u64)bu<<32) | (u32)n;
      if (kk < key[KK-1]){
        key[KK-1] = kk;
        #pragma unroll
        for (int t=KK-1;t>0;--t){
          u64 a=key[t-1], c=key[t];
          bool sw = c < a;
          key[t-1] = sw? c : a;
          key[t]   = sw? a : c;
        }
      }
    }
    int n_sel = 0;
    #pragma unroll 1
    for (int r=0;r<KK;r++){
      u64 m = key[0];
      #pragma unroll
      for (int mm=1;mm<64;mm<<=1){
        u64 om = __shfl_xor((unsigned long long)m, mm, 64);
        if (om < m) m = om;
      }
      if (k == r) n_sel = (int)(u32)m;
      if (key[0]==m){
        #pragma unroll
        for (int t=0;t<KK-1;t++) key[t]=key[t+1];
        key[KK-1]=~0ull;
      }
    }
    // ---- gather into wave-private LDS (no block barrier: DS in-order per wave) ------
    {
      const float* fp = feat + ((size_t)b*NN + (size_t)n_sel)*IND + part*16;
      float4 f0 = *(const float4*)(fp+0);
      float4 f1 = *(const float4*)(fp+4);
      float4 f2v = *(const float4*)(fp+8);
      float4 f3 = *(const float4*)(fp+12);
      float v[16] = {f0.x,f0.y,f0.z,f0.w, f1.x,f1.y,f1.z,f1.w,
                     f2v.x,f2v.y,f2v.z,f2v.w, f3.x,f3.y,f3.z,f3.w};
      #pragma unroll
      for (int c=0;c<16;c++) gw[(3+part*16+c)*16 + k] = v[c];
      if (part==0){
        float4 pp = P[n_sel];
        gw[0*16+k] = __fsub_rn(pp.x, qx);
        gw[1*16+k] = __fsub_rn(pp.y, qy);
        gw[2*16+k] = __fsub_rn(pp.z, qz);
      }
    }
    __builtin_amdgcn_wave_barrier();        // pin compiler order; HW DS is in-order
    int o = lane;
    float a0[16], a1[16];
    #pragma unroll
    for (int t=0;t<16;t++){ a0[t]=0.0f; a1[t]=0.0f; }
    #pragma unroll 4
    for (int j=0;j<CIN;j++){
      float w0 = W1[j*OD + o];
      float w1 = W1[j*OD + o + 64];
      #pragma unroll
      for (int t=0;t<16;t++){
        float gv = gw[j*16+t];
        a0[t]=fmaf(gv,w0,a0[t]); a1[t]=fmaf(gv,w1,a1[t]);
      }
    }
    float bb0 = b1[o], bb1 = b1[o+64];
    #pragma unroll
    for (int t=0;t<16;t++){
      hw[o*20+t]      = fmaxf(a0[t]+bb0, 0.0f);
      hw[(o+64)*20+t] = fmaxf(a1[t]+bb1, 0.0f);
    }
    __builtin_amdgcn_wave_barrier();
    float c0[16], c1[16];
    #pragma unroll
    for (int t=0;t<16;t++){ c0[t]=0.0f; c1[t]=0.0f; }
    #pragma unroll 4
    for (int j=0;j<OD;j++){
      float w0 = W2[j*OD + o];
      float w1 = W2[j*OD + o + 64];
      #pragma unroll
      for (int t=0;t<16;t++){
        float hv = hw[j*20+t];
        c0[t]=fmaf(hv,w0,c0[t]); c1[t]=fmaf(hv,w1,c1[t]);
      }
    }
    float m0=c0[0], m1=c1[0];
    #pragma unroll
    for (int t=1;t<16;t++){ m0=fmaxf(m0,c0[t]); m1=fmaxf(m1,c1[t]); }
    m0 += b2[o]; m1 += b2[o+64];
    float ssum = m0+m1;
    #pragma unroll
    for (int mm=1;mm<64;mm<<=1) ssum += __shfl_xor(ssum,mm,64);
    float mean = ssum * (1.0f/128.0f);
    float d0=m0-mean, d1=m1-mean;
    float sq = d0*d0 + d1*d1;
    #pragma unroll
    for (int mm=1;mm<64;mm<<=1) sq += __shfl_xor(sq,mm,64);
    float var = sq * (1.0f/128.0f);
    float x = var + 1e-5f;
    float r = rsqrtf(x);
    r = r * (1.5f - 0.5f*x*r*r);
    size_t obf = (size_t)q*OD;
    out_feat[obf+o]    = fmaf(d0*r, g_ln[o],    b_ln[o]);
    out_feat[obf+o+64] = fmaf(d1*r, g_ln[o+64], b_ln[o+64]);
  }
}

extern "C" void kernel_launch(void* const* d_in, const int* in_sizes, int n_in,
                              void* d_out, int out_size, void* d_ws, size_t ws_size,
                              hipStream_t stream){
  const float* xyz  = (const float*)d_in[0];
  const float* feat = (const float*)d_in[1];
  const float* W1   = (const float*)d_in[2];
  const float* b1   = (const float*)d_in[3];
  const float* W2   = (const float*)d_in[4];
  const float* b2   = (const float*)d_in[5];
  const float* lg   = (const float*)d_in[6];
  const float* lb   = (const float*)d_in[7];
  float* out = (float*)d_out;
  char* ws = (char*)d_ws;
  float4* pts = (float4*)ws;                          // 512 KB
  u32*   progress = (u32*)(ws + 524288);              // 16 B, zeroed by k_prep
  float* out_xyz  = out;
  float* out_feat = out + (size_t)BB*SS*3;

  hipFuncSetAttribute((const void*)k_fused,
                      hipFuncAttributeMaxDynamicSharedMemorySize, DYN_LDS);

  hipLaunchKernelGGL(k_prep,  dim3((BB*NN+255)/256), dim3(256), 0,       stream, xyz, pts, progress);
  hipLaunchKernelGGL(k_fused, dim3(GRID),            dim3(512), DYN_LDS, stream,
                     pts, out_xyz, feat, W1, b1, W2, b2, lg, lb, out_feat, progress);
}

// Round 15
// 2138.324 us; speedup vs baseline: 1.8246x; 1.0051x over previous
//
#include <hip/hip_runtime.h>
#include <stdint.h>

#define BB 4
#define NN 8192
#define SS 2048
#define KK 16
#define IND 64
#define CIN 67
#define OD 128

typedef unsigned int   u32;
typedef unsigned long long u64;
typedef float f2 __attribute__((ext_vector_type(2)));

#define TAG 0x5EED0000u
#define CW  252                      // consumer blocks
#define GRID (BB + CW)               // 256 blocks, 1/CU -> all co-resident
#define NWAVES (CW*8)                // 2016 consumer waves
#define SLICE 3632                   // floats per consumer wave slice (gbuf 1072 + hbuf 2560)
#define DYN_LDS (8*SLICE*4)          // 116224 B >= FPS's 98304 B coord need

template<int CTRL>
__device__ __forceinline__ float dpp_mv(float x){
  int xi = __builtin_bit_cast(int, x);
  int r  = __builtin_amdgcn_update_dpp(xi, xi, CTRL, 0xf, 0xf, false);
  return __builtin_bit_cast(float, r);
}

// ---------------- fused: blocks 0..3 = FPS producer; blocks 4..255 = knn+mlp consumers --
#define FPT 512
#define PPT (NN/FPT)   // 16
#define NW  (FPT/64)   // 8
__global__ __launch_bounds__(512) void k_fused(const float* __restrict__ xyz,
                                               float* __restrict__ out_xyz,
                                               const float* __restrict__ feat,
                                               const float* __restrict__ W1, const float* __restrict__ b1,
                                               const float* __restrict__ W2, const float* __restrict__ b2,
                                               const float* __restrict__ g_ln, const float* __restrict__ b_ln,
                                               float* __restrict__ out_feat,
                                               u32* __restrict__ progress){
  extern __shared__ float smem[];
  __shared__ u64 pkey[2][NW];
  __shared__ float ring[16*3];               // producer center ring (chunked store)
  int tid = threadIdx.x;
  int wid = tid >> 6, lane = tid & 63;

  if (blockIdx.x < BB){
    // =========================== FPS producer ==========================================
    #pragma clang fp contract(off)
    float* sx = smem;                 // [NN]
    float* sy = smem +   NN;          // [NN]
    float* sz = smem + 2*NN;          // [NN]
    int b = blockIdx.x;
    const float4* Xv = (const float4*)(xyz + (size_t)b*NN*3);  // 192B/thread, 16B aligned
    float f[48];
    #pragma unroll
    for (int v=0;v<12;v++){
      float4 t4 = Xv[tid*12 + v];
      f[4*v+0]=t4.x; f[4*v+1]=t4.y; f[4*v+2]=t4.z; f[4*v+3]=t4.w;
    }
    f2 X[PPT/2], Y[PPT/2], Z[PPT/2], D[PPT/2];
    #pragma unroll
    for (int jp=0;jp<PPT/2;jp++){
      int j0 = 2*jp, j1 = 2*jp+1;
      X[jp] = (f2){f[3*j0+0], f[3*j1+0]};
      Y[jp] = (f2){f[3*j0+1], f[3*j1+1]};
      Z[jp] = (f2){f[3*j0+2], f[3*j1+2]};
      D[jp] = (f2){1e10f, 1e10f};
      int n0 = tid*PPT + j0;
      sx[n0]=f[3*j0+0]; sx[n0+1]=f[3*j1+0];
      sy[n0]=f[3*j0+1]; sy[n0+1]=f[3*j1+1];
      sz[n0]=f[3*j0+2]; sz[n0+1]=f[3*j1+2];
    }
    const float* X0 = xyz + (size_t)b*NN*3;
    float cx=X0[0], cy=X0[1], cz=X0[2];      // uniform (scalar) loads
    size_t ob = (size_t)b*SS*3;
    if (tid==1){
      out_xyz[ob+0]=cx; out_xyz[ob+1]=cy; out_xyz[ob+2]=cz;
      ring[0]=cx; ring[1]=cy; ring[2]=cz;
      __hip_atomic_store(&progress[b], TAG|0u, __ATOMIC_RELEASE, __HIP_MEMORY_SCOPE_AGENT);
    }
    __syncthreads();

    for (int it=1; it<SS; ++it){
      f2 mm0 = (f2){-1.0f, -1.0f}, mm1 = (f2){-1.0f, -1.0f};
      #pragma unroll
      for (int jp=0;jp<PPT/2;jp+=2){
        f2 dx0 = X[jp] - cx,   dy0 = Y[jp] - cy,   dz0 = Z[jp] - cz;
        f2 dx1 = X[jp+1] - cx, dy1 = Y[jp+1] - cy, dz1 = Z[jp+1] - cz;
        f2 d0  = ((dx0*dx0) + (dy0*dy0)) + (dz0*dz0);   // ((dx2+dy2)+dz2), numpy rn order
        f2 d1  = ((dx1*dx1) + (dy1*dy1)) + (dz1*dz1);
        f2 nd0 = __builtin_elementwise_min(D[jp],   d0);
        f2 nd1 = __builtin_elementwise_min(D[jp+1], d1);
        D[jp]   = nd0;
        D[jp+1] = nd1;
        mm0 = __builtin_elementwise_max(mm0, nd0);
        mm1 = __builtin_elementwise_max(mm1, nd1);
      }
      f2 mm = __builtin_elementwise_max(mm0, mm1);
      float md = fmaxf(mm.x, mm.y);
      float m = md;
      m = fmaxf(m, dpp_mv<0x111>(m));
      m = fmaxf(m, dpp_mv<0x112>(m));
      m = fmaxf(m, dpp_mv<0x114>(m));
      m = fmaxf(m, dpp_mv<0x118>(m));
      m = fmaxf(m, dpp_mv<0x142>(m));
      m = fmaxf(m, dpp_mv<0x143>(m));
      float wmax = __builtin_bit_cast(float,
          __builtin_amdgcn_readlane(__builtin_bit_cast(int, m), 63));
      u64 ball = __ballot(md == wmax);
      int wl = __ffsll((unsigned long long)ball) - 1;
      if (lane == wl){
        int bj = 0;
        #pragma unroll
        for (int t=PPT-1;t>=0;--t){
          float v = (t&1)? D[t>>1].y : D[t>>1].x;
          if (v == wmax) bj = t;
        }
        int widx = tid*PPT + bj;
        pkey[it&1][wid] = ((u64)__float_as_uint(wmax) << 32) | (u32)~(u32)widx;
      }
      __syncthreads();
      u64 bk = pkey[it&1][0];
      #pragma unroll
      for (int w=1;w<NW;w++){
        u64 k2 = pkey[it&1][w];
        if (k2 > bk) bk = k2;
      }
      int gw = (int)~(u32)bk;
      cx = sx[gw]; cy = sy[gw]; cz = sz[gw];
      if (tid==1){                           // LDS ring write: no VMEM on critical path
        int rs = (it&15)*3;
        ring[rs]=cx; ring[rs+1]=cy; ring[rs+2]=cz;
      }
      if ((it & 15) == 15){
        if (wid==0 && lane<48){              // one coalesced 48-float chunk store
          size_t base = ob + (size_t)(it-15)*3;
          out_xyz[base + lane] = ring[lane];
        }
        if (tid==1){
          // RELEASE is mandatory: it emits vmcnt(0)+L2 writeback, making the plain
          // chunk stores visible across XCDs (R14's RELAXED publish served stale
          // centers -> wrong KNN. Guideline 16.)
          __hip_atomic_store(&progress[b], TAG|(u32)it,
                             __ATOMIC_RELEASE, __HIP_MEMORY_SCOPE_AGENT);
        }
      }
    }
    return;
  }

  // ============================ consumer: knn + mlp per wave ==========================
  int gid = (blockIdx.x - BB)*8 + wid;       // 0..2015
  float* gw = smem + wid*SLICE;              // wave-private gbuf [CIN][16]
  float* hw = gw + 1072;                     // wave-private hbuf [OD][20]
  int k = lane & 15, part = lane >> 4;
  const u32* ctru = (const u32*)out_xyz;

  for (int p = gid; p < BB*SS; p += NWAVES){
    int s = p >> 2, b = p & 3;
    int q = b*SS + s;
    for(;;){
      u32 v = __hip_atomic_load(&progress[b], __ATOMIC_RELAXED, __HIP_MEMORY_SCOPE_AGENT);
      if ((v & 0xFFFF0000u) == TAG && (v & 0xFFFFu) >= (u32)s) break;
      __builtin_amdgcn_s_sleep(64);
    }
    float qx = __builtin_bit_cast(float, __hip_atomic_load(&ctru[3*q+0], __ATOMIC_RELAXED, __HIP_MEMORY_SCOPE_AGENT));
    float qy = __builtin_bit_cast(float, __hip_atomic_load(&ctru[3*q+1], __ATOMIC_RELAXED, __HIP_MEMORY_SCOPE_AGENT));
    float qz = __builtin_bit_cast(float, __hip_atomic_load(&ctru[3*q+2], __ATOMIC_RELAXED, __HIP_MEMORY_SCOPE_AGENT));
    const float* Pb = xyz + (size_t)b*NN*3;
    float q2 = __fadd_rn(__fadd_rn(__fmul_rn(qx,qx),__fmul_rn(qy,qy)),__fmul_rn(qz,qz));
    // ---- KNN: exact (q2+x2)-2dot, x2 computed inline (same rn order as reference) ---
    u64 key[KK];
    #pragma unroll
    for (int t=0;t<KK;t++) key[t] = ~0ull;
    for (int i=0;i<NN/64;i++){
      int n = i*64 + lane;
      float px = Pb[3*n], py = Pb[3*n+1], pz = Pb[3*n+2];
      float x2  = __fadd_rn(__fadd_rn(__fmul_rn(px,px),__fmul_rn(py,py)),__fmul_rn(pz,pz));
      float dot = __fadd_rn(__fadd_rn(__fmul_rn(qx,px),__fmul_rn(qy,py)),__fmul_rn(qz,pz));
      float sd  = __fsub_rn(__fadd_rn(q2,x2), __fmul_rn(2.0f,dot));
      u32 bu = __float_as_uint(sd);
      bu ^= (u32)((int)bu >> 31) | 0x80000000u;
      u64 kk = ((u64)bu<<32) | (u32)n;
      if (kk < key[KK-1]){
        key[KK-1] = kk;
        #pragma unroll
        for (int t=KK-1;t>0;--t){
          u64 a=key[t-1], c=key[t];
          bool sw = c < a;
          key[t-1] = sw? c : a;
          key[t]   = sw? a : c;
        }
      }
    }
    int n_sel = 0;
    #pragma unroll 1
    for (int r=0;r<KK;r++){
      u64 m = key[0];
      #pragma unroll
      for (int mm=1;mm<64;mm<<=1){
        u64 om = __shfl_xor((unsigned long long)m, mm, 64);
        if (om < m) m = om;
      }
      if (k == r) n_sel = (int)(u32)m;
      if (key[0]==m){
        #pragma unroll
        for (int t=0;t<KK-1;t++) key[t]=key[t+1];
        key[KK-1]=~0ull;
      }
    }
    // ---- gather into wave-private LDS (no block barrier; DS in-order per wave) ------
    {
      const float* fp = feat + ((size_t)b*NN + (size_t)n_sel)*IND + part*16;
      float4 f0 = *(const float4*)(fp+0);
      float4 f1 = *(const float4*)(fp+4);
      float4 f2v = *(const float4*)(fp+8);
      float4 f3 = *(const float4*)(fp+12);
      float v[16] = {f0.x,f0.y,f0.z,f0.w, f1.x,f1.y,f1.z,f1.w,
                     f2v.x,f2v.y,f2v.z,f2v.w, f3.x,f3.y,f3.z,f3.w};
      #pragma unroll
      for (int c=0;c<16;c++) gw[(3+part*16+c)*16 + k] = v[c];
      if (part==0){
        float ppx = Pb[3*n_sel], ppy = Pb[3*n_sel+1], ppz = Pb[3*n_sel+2];
        gw[0*16+k] = __fsub_rn(ppx, qx);
        gw[1*16+k] = __fsub_rn(ppy, qy);
        gw[2*16+k] = __fsub_rn(ppz, qz);
      }
    }
    __builtin_amdgcn_wave_barrier();
    int o = lane;
    float a0[16], a1[16];
    #pragma unroll
    for (int t=0;t<16;t++){ a0[t]=0.0f; a1[t]=0.0f; }
    #pragma unroll 4
    for (int j=0;j<CIN;j++){
      float w0 = W1[j*OD + o];
      float w1 = W1[j*OD + o + 64];
      #pragma unroll
      for (int t=0;t<16;t++){
        float gv = gw[j*16+t];
        a0[t]=fmaf(gv,w0,a0[t]); a1[t]=fmaf(gv,w1,a1[t]);
      }
    }
    float bb0 = b1[o], bb1 = b1[o+64];
    #pragma unroll
    for (int t=0;t<16;t++){
      hw[o*20+t]      = fmaxf(a0[t]+bb0, 0.0f);
      hw[(o+64)*20+t] = fmaxf(a1[t]+bb1, 0.0f);
    }
    __builtin_amdgcn_wave_barrier();
    float c0[16], c1[16];
    #pragma unroll
    for (int t=0;t<16;t++){ c0[t]=0.0f; c1[t]=0.0f; }
    #pragma unroll 4
    for (int j=0;j<OD;j++){
      float w0 = W2[j*OD + o];
      float w1 = W2[j*OD + o + 64];
      #pragma unroll
      for (int t=0;t<16;t++){
        float hv = hw[j*20+t];
        c0[t]=fmaf(hv,w0,c0[t]); c1[t]=fmaf(hv,w1,c1[t]);
      }
    }
    float m0=c0[0], m1=c1[0];
    #pragma unroll
    for (int t=1;t<16;t++){ m0=fmaxf(m0,c0[t]); m1=fmaxf(m1,c1[t]); }
    m0 += b2[o]; m1 += b2[o+64];
    float ssum = m0+m1;
    #pragma unroll
    for (int mm=1;mm<64;mm<<=1) ssum += __shfl_xor(ssum,mm,64);
    float mean = ssum * (1.0f/128.0f);
    float d0=m0-mean, d1=m1-mean;
    float sq = d0*d0 + d1*d1;
    #pragma unroll
    for (int mm=1;mm<64;mm<<=1) sq += __shfl_xor(sq,mm,64);
    float var = sq * (1.0f/128.0f);
    float x = var + 1e-5f;
    float r = rsqrtf(x);
    r = r * (1.5f - 0.5f*x*r*r);
    size_t obf = (size_t)q*OD;
    out_feat[obf+o]    = fmaf(d0*r, g_ln[o],    b_ln[o]);
    out_feat[obf+o+64] = fmaf(d1*r, g_ln[o+64], b_ln[o+64]);
  }
}

extern "C" void kernel_launch(void* const* d_in, const int* in_sizes, int n_in,
                              void* d_out, int out_size, void* d_ws, size_t ws_size,
                              hipStream_t stream){
  const float* xyz  = (const float*)d_in[0];
  const float* feat = (const float*)d_in[1];
  const float* W1   = (const float*)d_in[2];
  const float* b1   = (const float*)d_in[3];
  const float* W2   = (const float*)d_in[4];
  const float* b2   = (const float*)d_in[5];
  const float* lg   = (const float*)d_in[6];
  const float* lb   = (const float*)d_in[7];
  float* out = (float*)d_out;
  u32* progress = (u32*)d_ws;                         // 16 B, zeroed below each call
  float* out_xyz  = out;
  float* out_feat = out + (size_t)BB*SS*3;

  hipFuncSetAttribute((const void*)k_fused,
                      hipFuncAttributeMaxDynamicSharedMemorySize, DYN_LDS);

  hipMemsetAsync(progress, 0, BB*sizeof(u32), stream);  // tag!=0x5EED -> not ready
  hipLaunchKernelGGL(k_fused, dim3(GRID), dim3(512), DYN_LDS, stream,
                     xyz, out_xyz, feat, W1, b1, W2, b2, lg, lb, out_feat, progress);
}

// Round 16
// 2129.755 us; speedup vs baseline: 1.8319x; 1.0040x over previous
//
#include <hip/hip_runtime.h>
#include <stdint.h>

#define BB 4
#define NN 8192
#define SS 2048
#define KK 16
#define IND 64
#define CIN 67
#define OD 128

typedef unsigned int   u32;
typedef unsigned long long u64;
typedef float f2 __attribute__((ext_vector_type(2)));

#define TAG 0x5EED0000u
#define CW  252                      // consumer blocks
#define GRID (BB + CW)               // 256 blocks, 1/CU -> all co-resident
#define NWAVES (CW*8)                // 2016 consumer waves
#define SLICE 3632                   // floats per consumer wave slice (gbuf 1072 + hbuf 2560)
#define DYN_LDS (8*SLICE*4)          // 116224 B >= FPS's 98304 B coord need

template<int CTRL>
__device__ __forceinline__ float dpp_mv(float x){
  int xi = __builtin_bit_cast(int, x);
  int r  = __builtin_amdgcn_update_dpp(xi, xi, CTRL, 0xf, 0xf, false);
  return __builtin_bit_cast(float, r);
}

// ---------------- fused: blocks 0..3 = FPS producer; blocks 4..255 = knn+mlp consumers --
#define FPT 512
#define PPT (NN/FPT)   // 16
#define NW  (FPT/64)   // 8
__global__ __launch_bounds__(512) void k_fused(const float* __restrict__ xyz,
                                               float* __restrict__ out_xyz,
                                               const float* __restrict__ feat,
                                               const float* __restrict__ W1, const float* __restrict__ b1,
                                               const float* __restrict__ W2, const float* __restrict__ b2,
                                               const float* __restrict__ g_ln, const float* __restrict__ b_ln,
                                               float* __restrict__ out_feat,
                                               u32* __restrict__ progress){
  extern __shared__ float smem[];
  __shared__ u64 pkey[2][NW];
  __shared__ float ring[16*3];               // producer center ring (chunked store)
  int tid = threadIdx.x;
  int wid = tid >> 6, lane = tid & 63;

  if (blockIdx.x < BB){
    // =========================== FPS producer ==========================================
    #pragma clang fp contract(off)
    float* sx = smem;                 // [NN]
    float* sy = smem +   NN;          // [NN]
    float* sz = smem + 2*NN;          // [NN]
    int b = blockIdx.x;
    const float4* Xv = (const float4*)(xyz + (size_t)b*NN*3);  // 192B/thread, 16B aligned
    float f[48];
    #pragma unroll
    for (int v=0;v<12;v++){
      float4 t4 = Xv[tid*12 + v];
      f[4*v+0]=t4.x; f[4*v+1]=t4.y; f[4*v+2]=t4.z; f[4*v+3]=t4.w;
    }
    f2 X[PPT/2], Y[PPT/2], Z[PPT/2], D[PPT/2];
    #pragma unroll
    for (int jp=0;jp<PPT/2;jp++){
      int j0 = 2*jp, j1 = 2*jp+1;
      X[jp] = (f2){f[3*j0+0], f[3*j1+0]};
      Y[jp] = (f2){f[3*j0+1], f[3*j1+1]};
      Z[jp] = (f2){f[3*j0+2], f[3*j1+2]};
      D[jp] = (f2){1e10f, 1e10f};
      int n0 = tid*PPT + j0;
      sx[n0]=f[3*j0+0]; sx[n0+1]=f[3*j1+0];
      sy[n0]=f[3*j0+1]; sy[n0+1]=f[3*j1+1];
      sz[n0]=f[3*j0+2]; sz[n0+1]=f[3*j1+2];
    }
    const float* X0 = xyz + (size_t)b*NN*3;
    float cx=X0[0], cy=X0[1], cz=X0[2];      // uniform (scalar) loads
    size_t ob = (size_t)b*SS*3;
    if (tid==1){
      out_xyz[ob+0]=cx; out_xyz[ob+1]=cy; out_xyz[ob+2]=cz;
      ring[0]=cx; ring[1]=cy; ring[2]=cz;
      __hip_atomic_store(&progress[b], TAG|0u, __ATOMIC_RELEASE, __HIP_MEMORY_SCOPE_AGENT);
    }
    __syncthreads();

    for (int it=1; it<SS; ++it){
      f2 mm0 = (f2){-1.0f, -1.0f}, mm1 = (f2){-1.0f, -1.0f};
      #pragma unroll
      for (int jp=0;jp<PPT/2;jp+=2){
        f2 dx0 = X[jp] - cx,   dy0 = Y[jp] - cy,   dz0 = Z[jp] - cz;
        f2 dx1 = X[jp+1] - cx, dy1 = Y[jp+1] - cy, dz1 = Z[jp+1] - cz;
        f2 d0  = ((dx0*dx0) + (dy0*dy0)) + (dz0*dz0);   // ((dx2+dy2)+dz2), numpy rn order
        f2 d1  = ((dx1*dx1) + (dy1*dy1)) + (dz1*dz1);
        f2 nd0 = __builtin_elementwise_min(D[jp],   d0);
        f2 nd1 = __builtin_elementwise_min(D[jp+1], d1);
        D[jp]   = nd0;
        D[jp+1] = nd1;
        mm0 = __builtin_elementwise_max(mm0, nd0);
        mm1 = __builtin_elementwise_max(mm1, nd1);
      }
      f2 mm = __builtin_elementwise_max(mm0, mm1);
      float md = fmaxf(mm.x, mm.y);
      float m = md;
      m = fmaxf(m, dpp_mv<0x111>(m));
      m = fmaxf(m, dpp_mv<0x112>(m));
      m = fmaxf(m, dpp_mv<0x114>(m));
      m = fmaxf(m, dpp_mv<0x118>(m));
      m = fmaxf(m, dpp_mv<0x142>(m));
      m = fmaxf(m, dpp_mv<0x143>(m));
      float wmax = __builtin_bit_cast(float,
          __builtin_amdgcn_readlane(__builtin_bit_cast(int, m), 63));
      u64 ball = __ballot(md == wmax);
      int wl = __ffsll((unsigned long long)ball) - 1;
      if (lane == wl){
        int bj = 0;
        #pragma unroll
        for (int t=PPT-1;t>=0;--t){
          float v = (t&1)? D[t>>1].y : D[t>>1].x;
          if (v == wmax) bj = t;
        }
        int widx = tid*PPT + bj;
        pkey[it&1][wid] = ((u64)__float_as_uint(wmax) << 32) | (u32)~(u32)widx;
      }
      __syncthreads();
      u64 bk = pkey[it&1][0];
      #pragma unroll
      for (int w=1;w<NW;w++){
        u64 k2 = pkey[it&1][w];
        if (k2 > bk) bk = k2;
      }
      int gw = (int)~(u32)bk;
      cx = sx[gw]; cy = sy[gw]; cz = sz[gw];
      if (tid==1){                           // LDS ring write: no VMEM on critical path
        int rs = (it&15)*3;
        ring[rs]=cx; ring[rs+1]=cy; ring[rs+2]=cz;
      }
      if ((it & 15) == 15){
        if (wid==0 && lane<48){              // one coalesced 48-float chunk store (plain)
          size_t base = ob + (size_t)(it-15)*3;
          out_xyz[base + lane] = ring[lane];
        }
        // RELEASE only every 128 iters: one release (by tid1, wave 0) drains ALL of
        // wave 0's outstanding chunk stores via vmcnt(0)+L2 writeback, making every
        // center up to `it` visible across XCDs (Guideline 16). 16 releases instead of
        // 128 cuts the producer's drain stalls ~8x; consumer slack absorbs the coarser
        // watermark (tail still <=1 query/wave after the final release).
        if (tid==1 && ((it & 127) == 127)){
          __hip_atomic_store(&progress[b], TAG|(u32)it,
                             __ATOMIC_RELEASE, __HIP_MEMORY_SCOPE_AGENT);
        }
      }
    }
    return;
  }

  // ============================ consumer: knn + mlp per wave ==========================
  int gid = (blockIdx.x - BB)*8 + wid;       // 0..2015
  float* gw = smem + wid*SLICE;              // wave-private gbuf [CIN][16]
  float* hw = gw + 1072;                     // wave-private hbuf [OD][20]
  int k = lane & 15, part = lane >> 4;
  const u32* ctru = (const u32*)out_xyz;

  for (int p = gid; p < BB*SS; p += NWAVES){
    int s = p >> 2, b = p & 3;
    int q = b*SS + s;
    for(;;){
      u32 v = __hip_atomic_load(&progress[b], __ATOMIC_RELAXED, __HIP_MEMORY_SCOPE_AGENT);
      if ((v & 0xFFFF0000u) == TAG && (v & 0xFFFFu) >= (u32)s) break;
      __builtin_amdgcn_s_sleep(64);
    }
    float qx = __builtin_bit_cast(float, __hip_atomic_load(&ctru[3*q+0], __ATOMIC_RELAXED, __HIP_MEMORY_SCOPE_AGENT));
    float qy = __builtin_bit_cast(float, __hip_atomic_load(&ctru[3*q+1], __ATOMIC_RELAXED, __HIP_MEMORY_SCOPE_AGENT));
    float qz = __builtin_bit_cast(float, __hip_atomic_load(&ctru[3*q+2], __ATOMIC_RELAXED, __HIP_MEMORY_SCOPE_AGENT));
    const float* Pb = xyz + (size_t)b*NN*3;
    float q2 = __fadd_rn(__fadd_rn(__fmul_rn(qx,qx),__fmul_rn(qy,qy)),__fmul_rn(qz,qz));
    // ---- KNN: exact (q2+x2)-2dot, x2 computed inline (same rn order as reference) ---
    u64 key[KK];
    #pragma unroll
    for (int t=0;t<KK;t++) key[t] = ~0ull;
    for (int i=0;i<NN/64;i++){
      int n = i*64 + lane;
      float px = Pb[3*n], py = Pb[3*n+1], pz = Pb[3*n+2];
      float x2  = __fadd_rn(__fadd_rn(__fmul_rn(px,px),__fmul_rn(py,py)),__fmul_rn(pz,pz));
      float dot = __fadd_rn(__fadd_rn(__fmul_rn(qx,px),__fmul_rn(qy,py)),__fmul_rn(qz,pz));
      float sd  = __fsub_rn(__fadd_rn(q2,x2), __fmul_rn(2.0f,dot));
      u32 bu = __float_as_uint(sd);
      bu ^= (u32)((int)bu >> 31) | 0x80000000u;
      u64 kk = ((u64)bu<<32) | (u32)n;
      if (kk < key[KK-1]){
        key[KK-1] = kk;
        #pragma unroll
        for (int t=KK-1;t>0;--t){
          u64 a=key[t-1], c=key[t];
          bool sw = c < a;
          key[t-1] = sw? c : a;
          key[t]   = sw? a : c;
        }
      }
    }
    int n_sel = 0;
    #pragma unroll 1
    for (int r=0;r<KK;r++){
      u64 m = key[0];
      #pragma unroll
      for (int mm=1;mm<64;mm<<=1){
        u64 om = __shfl_xor((unsigned long long)m, mm, 64);
        if (om < m) m = om;
      }
      if (k == r) n_sel = (int)(u32)m;
      if (key[0]==m){
        #pragma unroll
        for (int t=0;t<KK-1;t++) key[t]=key[t+1];
        key[KK-1]=~0ull;
      }
    }
    // ---- gather into wave-private LDS (no block barrier; DS in-order per wave) ------
    {
      const float* fp = feat + ((size_t)b*NN + (size_t)n_sel)*IND + part*16;
      float4 f0 = *(const float4*)(fp+0);
      float4 f1 = *(const float4*)(fp+4);
      float4 f2v = *(const float4*)(fp+8);
      float4 f3 = *(const float4*)(fp+12);
      float v[16] = {f0.x,f0.y,f0.z,f0.w, f1.x,f1.y,f1.z,f1.w,
                     f2v.x,f2v.y,f2v.z,f2v.w, f3.x,f3.y,f3.z,f3.w};
      #pragma unroll
      for (int c=0;c<16;c++) gw[(3+part*16+c)*16 + k] = v[c];
      if (part==0){
        float ppx = Pb[3*n_sel], ppy = Pb[3*n_sel+1], ppz = Pb[3*n_sel+2];
        gw[0*16+k] = __fsub_rn(ppx, qx);
        gw[1*16+k] = __fsub_rn(ppy, qy);
        gw[2*16+k] = __fsub_rn(ppz, qz);
      }
    }
    __builtin_amdgcn_wave_barrier();
    int o = lane;
    float a0[16], a1[16];
    #pragma unroll
    for (int t=0;t<16;t++){ a0[t]=0.0f; a1[t]=0.0f; }
    #pragma unroll 4
    for (int j=0;j<CIN;j++){
      float w0 = W1[j*OD + o];
      float w1 = W1[j*OD + o + 64];
      #pragma unroll
      for (int t=0;t<16;t++){
        float gv = gw[j*16+t];
        a0[t]=fmaf(gv,w0,a0[t]); a1[t]=fmaf(gv,w1,a1[t]);
      }
    }
    float bb0 = b1[o], bb1 = b1[o+64];
    #pragma unroll
    for (int t=0;t<16;t++){
      hw[o*20+t]      = fmaxf(a0[t]+bb0, 0.0f);
      hw[(o+64)*20+t] = fmaxf(a1[t]+bb1, 0.0f);
    }
    __builtin_amdgcn_wave_barrier();
    float c0[16], c1[16];
    #pragma unroll
    for (int t=0;t<16;t++){ c0[t]=0.0f; c1[t]=0.0f; }
    #pragma unroll 4
    for (int j=0;j<OD;j++){
      float w0 = W2[j*OD + o];
      float w1 = W2[j*OD + o + 64];
      #pragma unroll
      for (int t=0;t<16;t++){
        float hv = hw[j*20+t];
        c0[t]=fmaf(hv,w0,c0[t]); c1[t]=fmaf(hv,w1,c1[t]);
      }
    }
    float m0=c0[0], m1=c1[0];
    #pragma unroll
    for (int t=1;t<16;t++){ m0=fmaxf(m0,c0[t]); m1=fmaxf(m1,c1[t]); }
    m0 += b2[o]; m1 += b2[o+64];
    float ssum = m0+m1;
    #pragma unroll
    for (int mm=1;mm<64;mm<<=1) ssum += __shfl_xor(ssum,mm,64);
    float mean = ssum * (1.0f/128.0f);
    float d0=m0-mean, d1=m1-mean;
    float sq = d0*d0 + d1*d1;
    #pragma unroll
    for (int mm=1;mm<64;mm<<=1) sq += __shfl_xor(sq,mm,64);
    float var = sq * (1.0f/128.0f);
    float x = var + 1e-5f;
    float r = rsqrtf(x);
    r = r * (1.5f - 0.5f*x*r*r);
    size_t obf = (size_t)q*OD;
    out_feat[obf+o]    = fmaf(d0*r, g_ln[o],    b_ln[o]);
    out_feat[obf+o+64] = fmaf(d1*r, g_ln[o+64], b_ln[o+64]);
  }
}

extern "C" void kernel_launch(void* const* d_in, const int* in_sizes, int n_in,
                              void* d_out, int out_size, void* d_ws, size_t ws_size,
                              hipStream_t stream){
  const float* xyz  = (const float*)d_in[0];
  const float* feat = (const float*)d_in[1];
  const float* W1   = (const float*)d_in[2];
  const float* b1   = (const float*)d_in[3];
  const float* W2   = (const float*)d_in[4];
  const float* b2   = (const float*)d_in[5];
  const float* lg   = (const float*)d_in[6];
  const float* lb   = (const float*)d_in[7];
  float* out = (float*)d_out;
  u32* progress = (u32*)d_ws;                         // 16 B, zeroed below each call
  float* out_xyz  = out;
  float* out_feat = out + (size_t)BB*SS*3;

  hipFuncSetAttribute((const void*)k_fused,
                      hipFuncAttributeMaxDynamicSharedMemorySize, DYN_LDS);

  hipMemsetAsync(progress, 0, BB*sizeof(u32), stream);  // tag!=0x5EED -> not ready
  hipLaunchKernelGGL(k_fused, dim3(GRID), dim3(512), DYN_LDS, stream,
                     xyz, out_xyz, feat, W1, b1, W2, b2, lg, lb, out_feat, progress);
}